// Round 7
// baseline (13025.006 us; speedup 1.0000x reference)
//
#include <hip/hip_runtime.h>
#include <math.h>

#define Bc 16
#define Tc 2048
#define Dc 512
#define Hc 1024
#define Rc 16

// ---------------------------------------------------------------------------
// GEMM: out[M,1024] = X[M,512] @ W[512,1024], M = 32768.
// ---------------------------------------------------------------------------
__global__ __launch_bounds__(256) void gemm_xw(const float* __restrict__ X,
                                               const float* __restrict__ W,
                                               float* __restrict__ out)
{
    __shared__ float As[16][128];
    __shared__ float Bs[16][64];
    const int tid = threadIdx.x;
    const int m0 = blockIdx.x * 128;
    const int n0 = blockIdx.y * 64;
    const int tx = tid & 15, ty = tid >> 4;
    const int am = tid >> 2, ak = (tid & 3) * 4;
    const int bk = tid >> 4, bn = (tid & 15) * 4;
    float acc[8][4] = {};
    for (int k0 = 0; k0 < 512; k0 += 16) {
        if (k0) __syncthreads();
        float4 a0 = *(const float4*)&X[(size_t)(m0 + am) * 512 + k0 + ak];
        float4 a1 = *(const float4*)&X[(size_t)(m0 + am + 64) * 512 + k0 + ak];
        float4 bv = *(const float4*)&W[(size_t)(k0 + bk) * 1024 + n0 + bn];
        As[ak + 0][am] = a0.x; As[ak + 1][am] = a0.y;
        As[ak + 2][am] = a0.z; As[ak + 3][am] = a0.w;
        As[ak + 0][am + 64] = a1.x; As[ak + 1][am + 64] = a1.y;
        As[ak + 2][am + 64] = a1.z; As[ak + 3][am + 64] = a1.w;
        *(float4*)&Bs[bk][bn] = bv;
        __syncthreads();
        #pragma unroll
        for (int kk = 0; kk < 16; ++kk) {
            float4 x0 = *(const float4*)&As[kk][ty * 8];
            float4 x1 = *(const float4*)&As[kk][ty * 8 + 4];
            float4 y  = *(const float4*)&Bs[kk][tx * 4];
            float a[8] = {x0.x, x0.y, x0.z, x0.w, x1.x, x1.y, x1.z, x1.w};
            float bb[4] = {y.x, y.y, y.z, y.w};
            #pragma unroll
            for (int i = 0; i < 8; ++i)
                #pragma unroll
                for (int j = 0; j < 4; ++j)
                    acc[i][j] += a[i] * bb[j];
        }
    }
    #pragma unroll
    for (int i = 0; i < 8; ++i) {
        float4 r;
        r.x = acc[i][0]; r.y = acc[i][1]; r.z = acc[i][2]; r.w = acc[i][3];
        *(float4*)&out[(size_t)(m0 + ty * 8 + i) * 1024 + n0 + tx * 4] = r;
    }
}

// ---------------------------------------------------------------------------
// q, k, lambda projections.
// ---------------------------------------------------------------------------
__global__ __launch_bounds__(256) void qkl_kernel(const float* __restrict__ X,
    const float* __restrict__ Wq, const float* __restrict__ Wk,
    const float* __restrict__ Wd, const float* __restrict__ bd,
    float* __restrict__ q, float* __restrict__ k, float* __restrict__ lam)
{
    __shared__ float xs[8 * 512];
    const int tid = threadIdx.x;
    const size_t row0 = (size_t)blockIdx.x * 8;
    #pragma unroll
    for (int c = 0; c < 4; ++c) {
        int f = (c * 256 + tid) * 4;
        *(float4*)&xs[f] = *(const float4*)&X[row0 * 512 + f];
    }
    __syncthreads();
    for (int t = tid; t < 264; t += 256) {
        int r = t / 33, c = t - r * 33;
        const float* xr = &xs[r * 512];
        const float* Wp; int ldw;
        if (c < 16)      { Wp = Wq + c;        ldw = 16; }
        else if (c < 32) { Wp = Wk + (c - 16); ldw = 16; }
        else             { Wp = Wd;            ldw = 1;  }
        float s = 0.f;
        for (int kk = 0; kk < 512; ++kk) s += xr[kk] * Wp[(size_t)kk * ldw];
        if (c < 16)      q[(row0 + r) * 16 + c] = s;
        else if (c < 32) k[(row0 + r) * 16 + (c - 16)] = s;
        else             lam[row0 + r] = 1.f / (1.f + expf(-(s + bd[0])));
    }
}

// ---------------------------------------------------------------------------
// Fused recurrence, R7: 320 threads = 4 compute waves + 1 service wave.
//   waves 0-3 (tid<256): poll h (self-signaling +-4, sc0 sc1) -> stage LDS
//     -> barrier B -> matvec + in-wave butterfly -> red2 -> barrier C ->
//     loop straight into polling t+1 (depends only on OTHER WGs).
//   wave 4 (tid>=256): fast-weight scan (F, pre in REGISTERS, prefetched
//     inputs) hidden under the poll; after barrier C it is the finisher:
//     4 LDS reads + tanh + sc-store -- the ONLY producer-side work on the
//     inter-WG critical path.
// ---------------------------------------------------------------------------
__global__ __launch_bounds__(320, 1) void rec_fused(
    const float* __restrict__ Wh, const float* __restrict__ qg,
    const float* __restrict__ kg, const float* __restrict__ vg,
    const float* __restrict__ lamg, const float* __restrict__ bias,
    float* __restrict__ out0, float* __restrict__ hfin,
    float* __restrict__ Ffin, float* __restrict__ hbuf)
{
    __shared__ float hs[4 * 1280];     // phys(b,k) = b*1280 + (k>>4)*20 + (k&15)
    __shared__ float red2[2][256];     // [buf][wv*64 + col*4 + b]

    const int tid = threadIdx.x;
    const int w = blockIdx.x;
    const int sl = w & 63, g = w >> 6;
    const int c0 = sl * 16;
    const bool isC = (tid < 256);      // compute waves
    const bool isS = (tid >= 256);     // service wave (scan + finisher)
    const int kp = (tid >> 2) & 63;    // k-part (16 k's) for compute threads
    const int cg = tid & 3;            // col group
    const int wv = tid >> 6;           // wave id 0..4
    const int j64 = tid & 63;
    const int sb = j64 >> 4, scol = j64 & 15;   // service (b, col)
    const int sbg = g * 4 + sb;

    // Weights (compute threads only); all indices compile-time.
    float wr[64];
    #pragma unroll
    for (int i = 0; i < 16; ++i) {
        if (isC) {
            float4 w4 = *(const float4*)&Wh[(size_t)(kp * 16 + i) * 1024 + c0 + cg * 4];
            wr[i * 4 + 0] = w4.x; wr[i * 4 + 1] = w4.y;
            wr[i * 4 + 2] = w4.z; wr[i * 4 + 3] = w4.w;
        } else {
            wr[i * 4 + 0] = 0.f; wr[i * 4 + 1] = 0.f;
            wr[i * 4 + 2] = 0.f; wr[i * 4 + 3] = 0.f;
        }
    }

    // Service-wave state: F + prefetched inputs, all in registers.
    float F[16];
    #pragma unroll
    for (int r = 0; r < 16; ++r) F[r] = 0.f;
    float bias_r = 0.f, plam = 0.f, pv = 0.f, pxw = 0.f;
    float4 pq[4], pk4[4];
    if (isS) {
        bias_r = bias[c0 + scol];
        const size_t row = (size_t)sbg * Tc;            // t = 0 inputs
        plam = lamg[row];
        pv   = vg[row * Hc + c0 + scol];
        pxw  = out0[row * Hc + c0 + scol];
        const float* qp  = qg + row * 16;
        const float* kpp = kg + row * 16;
        #pragma unroll
        for (int r4 = 0; r4 < 4; ++r4) {
            pq[r4]  = *(const float4*)(qp + r4 * 4);
            pk4[r4] = *(const float4*)(kpp + r4 * 4);
        }
    }

    for (int t = 0; t < Tc; ++t) {
        const int buf = t & 1;
        float* h_rd = hbuf + (t & 1) * (Bc * Hc) + g * 4096;
        float* h_wr = hbuf + ((t + 1) & 1) * (Bc * Hc) + g * 4096;
        const float off_r = ((t >> 1) & 1) ? 4.0f : 0.0f;
        const float off_w = (((t + 1) >> 1) & 1) ? 4.0f : 0.0f;

        // ---- service wave: scan step t (hidden under compute waves' poll) ----
        float pre_val = 0.f;
        if (isS) {
            float rd = 0.f;
            #pragma unroll
            for (int r4 = 0; r4 < 4; ++r4) {
                float f0 = F[r4 * 4 + 0], f1 = F[r4 * 4 + 1];
                float f2 = F[r4 * 4 + 2], f3 = F[r4 * 4 + 3];
                f0 = plam * f0 + pv * pk4[r4].x; rd += f0 * pq[r4].x;
                f1 = plam * f1 + pv * pk4[r4].y; rd += f1 * pq[r4].y;
                f2 = plam * f2 + pv * pk4[r4].z; rd += f2 * pq[r4].z;
                f3 = plam * f3 + pv * pk4[r4].w; rd += f3 * pq[r4].w;
                F[r4 * 4 + 0] = f0; F[r4 * 4 + 1] = f1;
                F[r4 * 4 + 2] = f2; F[r4 * 4 + 3] = f3;
            }
            pre_val = pxw + rd + bias_r;
            if (t == Tc - 1) {
                #pragma unroll
                for (int r = 0; r < 16; ++r)
                    Ffin[((size_t)sbg * Hc + c0 + scol) * 16 + r] = F[r];
            } else {
                const size_t row = (size_t)sbg * Tc + (t + 1);
                plam = lamg[row];
                pv   = vg[row * Hc + c0 + scol];
                pxw  = out0[row * Hc + c0 + scol];
                const float* qp  = qg + row * 16;
                const float* kpp = kg + row * 16;
                #pragma unroll
                for (int r4 = 0; r4 < 4; ++r4) {
                    pq[r4]  = *(const float4*)(qp + r4 * 4);
                    pk4[r4] = *(const float4*)(kpp + r4 * 4);
                }
            }
        }

        // ---- compute waves: poll own window, stage into hs ----
        if (isC) {
            const int chunk = tid >> 2, coff = (tid & 3) * 4;
            float* base = &hs[chunk * 20 + coff];
            if (t > 0) {
                const float lo = off_r - 1.5f, hi = off_r + 1.5f;
                const float* p0 = h_rd + tid * 4;
                const float* p1 = p0 + 1024;
                const float* p2 = p0 + 2048;
                const float* p3 = p0 + 3072;
                float4 r0, r1, r2, r3;
                while (1) {
                    asm volatile(
                        "global_load_dwordx4 %0, %4, off sc0 sc1\n\t"
                        "global_load_dwordx4 %1, %5, off sc0 sc1\n\t"
                        "global_load_dwordx4 %2, %6, off sc0 sc1\n\t"
                        "global_load_dwordx4 %3, %7, off sc0 sc1\n\t"
                        "s_waitcnt vmcnt(0)"
                        : "=&v"(r0), "=&v"(r1), "=&v"(r2), "=&v"(r3)
                        : "v"(p0), "v"(p1), "v"(p2), "v"(p3)
                        : "memory");
                    bool ok = r0.x > lo && r0.x < hi && r0.y > lo && r0.y < hi
                           && r0.z > lo && r0.z < hi && r0.w > lo && r0.w < hi
                           && r1.x > lo && r1.x < hi && r1.y > lo && r1.y < hi
                           && r1.z > lo && r1.z < hi && r1.w > lo && r1.w < hi
                           && r2.x > lo && r2.x < hi && r2.y > lo && r2.y < hi
                           && r2.z > lo && r2.z < hi && r2.w > lo && r2.w < hi
                           && r3.x > lo && r3.x < hi && r3.y > lo && r3.y < hi
                           && r3.z > lo && r3.z < hi && r3.w > lo && r3.w < hi;
                    if (ok) break;
                }
                r0.x -= off_r; r0.y -= off_r; r0.z -= off_r; r0.w -= off_r;
                r1.x -= off_r; r1.y -= off_r; r1.z -= off_r; r1.w -= off_r;
                r2.x -= off_r; r2.y -= off_r; r2.z -= off_r; r2.w -= off_r;
                r3.x -= off_r; r3.y -= off_r; r3.z -= off_r; r3.w -= off_r;
                *(float4*)(base + 0 * 1280) = r0;
                *(float4*)(base + 1 * 1280) = r1;
                *(float4*)(base + 2 * 1280) = r2;
                *(float4*)(base + 3 * 1280) = r3;
            } else {
                float4 z = {0.f, 0.f, 0.f, 0.f};
                *(float4*)(base + 0 * 1280) = z;
                *(float4*)(base + 1 * 1280) = z;
                *(float4*)(base + 2 * 1280) = z;
                *(float4*)(base + 3 * 1280) = z;
            }
        }
        __syncthreads();                       // B: hs ready

        if (isC) {
            // ---- matvec: 16 b128 LDS reads, 256 FMAs per thread ----
            float acc[16];
            #pragma unroll
            for (int z = 0; z < 16; ++z) acc[z] = 0.f;
            #pragma unroll
            for (int b = 0; b < 4; ++b) {
                const float* hb = &hs[b * 1280 + kp * 20];
                #pragma unroll
                for (int e = 0; e < 4; ++e) {
                    float4 h4 = *(const float4*)(hb + e * 4);
                    #pragma unroll
                    for (int j = 0; j < 4; ++j)
                        acc[j * 4 + b] += h4.x * wr[(e * 4 + 0) * 4 + j]
                                        + h4.y * wr[(e * 4 + 1) * 4 + j]
                                        + h4.z * wr[(e * 4 + 2) * 4 + j]
                                        + h4.w * wr[(e * 4 + 3) * 4 + j];
                }
            }
            // ---- in-wave butterfly over 16 k-parts ----
            #pragma unroll
            for (int z = 0; z < 16; ++z) {
                float s = acc[z];
                s += __shfl_xor(s, 4);
                s += __shfl_xor(s, 8);
                s += __shfl_xor(s, 16);
                s += __shfl_xor(s, 32);
                acc[z] = s;
            }
            if (j64 < 4) {                     // j64 == cg on these lanes
                #pragma unroll
                for (int j = 0; j < 4; ++j) {
                    float4 r4;
                    r4.x = acc[j * 4 + 0]; r4.y = acc[j * 4 + 1];
                    r4.z = acc[j * 4 + 2]; r4.w = acc[j * 4 + 3];
                    *(float4*)&red2[buf][wv * 64 + (j64 * 4 + j) * 4] = r4;
                }
            }
        }
        __syncthreads();                       // C: red2 ready

        // ---- service wave: finisher (the only producer-side critical work) ----
        if (isS) {
            float tot = pre_val;
            #pragma unroll
            for (int ww = 0; ww < 4; ++ww)
                tot += red2[buf][ww * 64 + scol * 4 + sb];
            float hv = tanhf(tot);
            float sv = hv + off_w;             // self-signaling store first
            float* hp = h_wr + sb * 1024 + c0 + scol;
            asm volatile(
                "global_store_dword %0, %1, off sc0 sc1"
                :: "v"(hp), "v"(sv) : "memory");
            size_t oidx = ((size_t)sbg * Tc + t) * Hc + c0 + scol;
            out0[oidx] = hv;
            if (t == Tc - 1) hfin[(size_t)sbg * Hc + c0 + scol] = hv;
        }
    }
}

// ---------------------------------------------------------------------------
extern "C" void kernel_launch(void* const* d_in, const int* in_sizes, int n_in,
                              void* d_out, int out_size, void* d_ws, size_t ws_size,
                              hipStream_t stream)
{
    const float* x    = (const float*)d_in[0];
    const float* Wx   = (const float*)d_in[1];
    const float* Wh   = (const float*)d_in[2];
    const float* Wq   = (const float*)d_in[3];
    const float* Wk   = (const float*)d_in[4];
    const float* Wv   = (const float*)d_in[5];
    const float* Wd   = (const float*)d_in[6];
    const float* bias = (const float*)d_in[7];
    const float* bd   = (const float*)d_in[8];

    float* out0 = (float*)d_out;                    // (B,T,H): xw, then h
    float* hfin = out0 + (size_t)Bc * Tc * Hc;      // (B,H)
    float* Ffin = hfin + (size_t)Bc * Hc;           // (B,H,R)

    float* wsf  = (float*)d_ws;
    float* v    = wsf;                               // B*T*H
    float* q    = v + (size_t)Bc * Tc * Hc;          // B*T*R
    float* k    = q + (size_t)Bc * Tc * Rc;          // B*T*R
    float* lam  = k + (size_t)Bc * Tc * Rc;          // B*T
    float* hbuf = lam + (size_t)Bc * Tc;             // 2 * B*H ping-pong

    // 0x7F7F7F7F == 3.39e38f: invalid under both offsets -> poll-safe init.
    hipMemsetAsync(hbuf, 0x7F, 2 * (size_t)Bc * Hc * sizeof(float), stream);

    dim3 gg(256, 16);
    gemm_xw<<<gg, 256, 0, stream>>>(x, Wx, out0);   // xw -> out0
    gemm_xw<<<gg, 256, 0, stream>>>(x, Wv, v);      // v  -> ws
    qkl_kernel<<<4096, 256, 0, stream>>>(x, Wq, Wk, Wd, bd, q, k, lam);
    rec_fused<<<256, 320, 0, stream>>>(Wh, q, k, v, lam, bias,
                                       out0, hfin, Ffin, hbuf);
}

// Round 8
// 7530.639 us; speedup vs baseline: 1.7296x; 1.7296x over previous
//
#include <hip/hip_runtime.h>
#include <math.h>

#define Bc 16
#define Tc 2048
#define Dc 512
#define Hc 1024
#define Rc 16

// ---------------------------------------------------------------------------
// GEMM: out[M,1024] = X[M,512] @ W[512,1024], M = 32768.
// ---------------------------------------------------------------------------
__global__ __launch_bounds__(256) void gemm_xw(const float* __restrict__ X,
                                               const float* __restrict__ W,
                                               float* __restrict__ out)
{
    __shared__ float As[16][128];
    __shared__ float Bs[16][64];
    const int tid = threadIdx.x;
    const int m0 = blockIdx.x * 128;
    const int n0 = blockIdx.y * 64;
    const int tx = tid & 15, ty = tid >> 4;
    const int am = tid >> 2, ak = (tid & 3) * 4;
    const int bk = tid >> 4, bn = (tid & 15) * 4;
    float acc[8][4] = {};
    for (int k0 = 0; k0 < 512; k0 += 16) {
        if (k0) __syncthreads();
        float4 a0 = *(const float4*)&X[(size_t)(m0 + am) * 512 + k0 + ak];
        float4 a1 = *(const float4*)&X[(size_t)(m0 + am + 64) * 512 + k0 + ak];
        float4 bv = *(const float4*)&W[(size_t)(k0 + bk) * 1024 + n0 + bn];
        As[ak + 0][am] = a0.x; As[ak + 1][am] = a0.y;
        As[ak + 2][am] = a0.z; As[ak + 3][am] = a0.w;
        As[ak + 0][am + 64] = a1.x; As[ak + 1][am + 64] = a1.y;
        As[ak + 2][am + 64] = a1.z; As[ak + 3][am + 64] = a1.w;
        *(float4*)&Bs[bk][bn] = bv;
        __syncthreads();
        #pragma unroll
        for (int kk = 0; kk < 16; ++kk) {
            float4 x0 = *(const float4*)&As[kk][ty * 8];
            float4 x1 = *(const float4*)&As[kk][ty * 8 + 4];
            float4 y  = *(const float4*)&Bs[kk][tx * 4];
            float a[8] = {x0.x, x0.y, x0.z, x0.w, x1.x, x1.y, x1.z, x1.w};
            float bb[4] = {y.x, y.y, y.z, y.w};
            #pragma unroll
            for (int i = 0; i < 8; ++i)
                #pragma unroll
                for (int j = 0; j < 4; ++j)
                    acc[i][j] += a[i] * bb[j];
        }
    }
    #pragma unroll
    for (int i = 0; i < 8; ++i) {
        float4 r;
        r.x = acc[i][0]; r.y = acc[i][1]; r.z = acc[i][2]; r.w = acc[i][3];
        *(float4*)&out[(size_t)(m0 + ty * 8 + i) * 1024 + n0 + tx * 4] = r;
    }
}

// ---------------------------------------------------------------------------
// q, k, lambda projections.
// ---------------------------------------------------------------------------
__global__ __launch_bounds__(256) void qkl_kernel(const float* __restrict__ X,
    const float* __restrict__ Wq, const float* __restrict__ Wk,
    const float* __restrict__ Wd, const float* __restrict__ bd,
    float* __restrict__ q, float* __restrict__ k, float* __restrict__ lam)
{
    __shared__ float xs[8 * 512];
    const int tid = threadIdx.x;
    const size_t row0 = (size_t)blockIdx.x * 8;
    #pragma unroll
    for (int c = 0; c < 4; ++c) {
        int f = (c * 256 + tid) * 4;
        *(float4*)&xs[f] = *(const float4*)&X[row0 * 512 + f];
    }
    __syncthreads();
    for (int t = tid; t < 264; t += 256) {
        int r = t / 33, c = t - r * 33;
        const float* xr = &xs[r * 512];
        const float* Wp; int ldw;
        if (c < 16)      { Wp = Wq + c;        ldw = 16; }
        else if (c < 32) { Wp = Wk + (c - 16); ldw = 16; }
        else             { Wp = Wd;            ldw = 1;  }
        float s = 0.f;
        for (int kk = 0; kk < 512; ++kk) s += xr[kk] * Wp[(size_t)kk * ldw];
        if (c < 16)      q[(row0 + r) * 16 + c] = s;
        else if (c < 32) k[(row0 + r) * 16 + (c - 16)] = s;
        else             lam[row0 + r] = 1.f / (1.f + expf(-(s + bd[0])));
    }
}

// ---------------------------------------------------------------------------
// Fused recurrence, R8: XCD-LOCAL exchange groups.
// 256 WGs: group g = bid&7 (2 batches: 2g, 2g+1), slice sl = bid>>3
// (32 cols). Under round-robin bid%8->XCD dispatch, a whole group shares
// one XCD L2 -> exchange via sc0-only (L1-bypass, L2-coherent) = short RTT.
// Correctness does NOT assume the mapping: WGs publish their XCC_ID; each
// consumer picks sc0 (same XCD) vs sc0 sc1 (cross XCD) per its producer,
// with sticky escalation to the slow path after 64 failed fast polls.
// Producers always store sc0 sc1 (device coherence point).
// Structure per WG (4 waves, R6-proven): wave3 also runs the fast-weight
// scan (F in LDS, prefetched inputs); wave0 lanes also run the finisher.
// ---------------------------------------------------------------------------
__global__ __launch_bounds__(256, 1) void rec_fused(
    const float* __restrict__ Wh, const float* __restrict__ qg,
    const float* __restrict__ kg, const float* __restrict__ vg,
    const float* __restrict__ lamg, const float* __restrict__ bias,
    float* __restrict__ out0, float* __restrict__ hfin,
    float* __restrict__ Ffin, float* __restrict__ hbuf,
    int* __restrict__ xcc_tab)
{
    __shared__ float hs[2 * 1152];     // phys(b,k) = b*1152 + (k>>5)*36 + (k&31)
    __shared__ float red2[2][256];     // [buf][wave*64 + cu*8 + z]
    __shared__ float pre_lds[2][64];   // [buf][bb*32 + ci]
    __shared__ float F_lds[64][17];    // fast-weight state, pad 17

    const int tid = threadIdx.x;
    const int bid = blockIdx.x;
    const int g = bid & 7, sl = bid >> 3;
    const int c0 = sl * 32;
    const int kp = tid >> 3;          // k-part: 32 k's (kp*32 .. +31)
    const int cu = tid & 7;           // col unit: 4 cols (c0 + cu*4 + j)
    const int wv = tid >> 6;

    // ---- publish my XCD id (value xcc+1; table memset to 0xFF each launch)
    const int my_xcc = __builtin_amdgcn_s_getreg(63508) & 0xF; // hwreg(20,0,32)
    if (tid == 0) {
        int val = my_xcc + 1;
        int* tp = xcc_tab + bid;
        asm volatile("global_store_dword %0, %1, off sc0 sc1"
                     :: "v"(tp), "v"(val) : "memory");
    }

    // ---- weights: 128 regs/thread, all indices compile-time
    float wr[128];
    #pragma unroll
    for (int i = 0; i < 32; ++i) {
        float4 w4 = *(const float4*)&Wh[(size_t)(kp * 32 + i) * 1024 + c0 + cu * 4];
        wr[i * 4 + 0] = w4.x; wr[i * 4 + 1] = w4.y;
        wr[i * 4 + 2] = w4.z; wr[i * 4 + 3] = w4.w;
    }

    // ---- stage/poll geometry: thread owns 8 h values of one batch
    const int sb_ = tid >> 7;                // batch-in-group 0/1
    const int f   = (tid & 127) * 8;         // col offset 0..1016
    float* stage_base = &hs[sb_ * 1152 + (f >> 5) * 36 + (f & 31)];

    // ---- scope detect: producer of my window
    int fastf;
    {
        const int prod_bid = (f >> 5) * 8 + g;
        const int* tp = xcc_tab + prod_bid;
        int tv;
        for (;;) {
            asm volatile("global_load_dword %0, %1, off sc0 sc1\n\t"
                         "s_waitcnt vmcnt(0)"
                         : "=&v"(tv) : "v"(tp) : "memory");
            if (tv != -1) break;
        }
        fastf = ((tv - 1) == my_xcc) ? 1 : 0;
    }

    // ---- roles
    const int j64 = tid & 63;
    const int fb = j64 >> 5, fci = j64 & 31;   // (batch-in-group, col-in-slice)
    const int bg = g * 2 + fb;                 // global batch
    const bool isScan = (tid >= 192);
    const bool isFin  = (tid < 64);

    float bias_r = 0.f, plam = 0.f, pv = 0.f, pxw = 0.f;
    float4 pq[4], pk4[4];
    if (isScan) {
        bias_r = bias[c0 + fci];
        #pragma unroll
        for (int r = 0; r < 16; ++r) F_lds[j64][r] = 0.f;
        const size_t row = (size_t)bg * Tc;             // t = 0 inputs
        plam = lamg[row];
        pv   = vg[row * Hc + c0 + fci];
        pxw  = out0[row * Hc + c0 + fci];
        const float* qp  = qg + row * 16;
        const float* kpp = kg + row * 16;
        #pragma unroll
        for (int r4 = 0; r4 < 4; ++r4) {
            pq[r4]  = *(const float4*)(qp + r4 * 4);
            pk4[r4] = *(const float4*)(kpp + r4 * 4);
        }
    }

    for (int t = 0; t < Tc; ++t) {
        const int buf = t & 1;
        float* h_rd = hbuf + (t & 1) * (16 * 1024) + g * 2048;
        float* h_wr = hbuf + ((t + 1) & 1) * (16 * 1024) + g * 2048;
        const float off_r = ((t >> 1) & 1) ? 4.0f : 0.0f;
        const float off_w = (((t + 1) >> 1) & 1) ? 4.0f : 0.0f;

        // ---- wave3: fast-weight scan (hidden under the poll) ----
        if (isScan) {
            float rd = 0.f;
            #pragma unroll
            for (int r4 = 0; r4 < 4; ++r4) {
                float f0 = F_lds[j64][r4 * 4 + 0];
                float f1 = F_lds[j64][r4 * 4 + 1];
                float f2 = F_lds[j64][r4 * 4 + 2];
                float f3 = F_lds[j64][r4 * 4 + 3];
                f0 = plam * f0 + pv * pk4[r4].x; rd += f0 * pq[r4].x;
                f1 = plam * f1 + pv * pk4[r4].y; rd += f1 * pq[r4].y;
                f2 = plam * f2 + pv * pk4[r4].z; rd += f2 * pq[r4].z;
                f3 = plam * f3 + pv * pk4[r4].w; rd += f3 * pq[r4].w;
                F_lds[j64][r4 * 4 + 0] = f0;
                F_lds[j64][r4 * 4 + 1] = f1;
                F_lds[j64][r4 * 4 + 2] = f2;
                F_lds[j64][r4 * 4 + 3] = f3;
            }
            pre_lds[buf][j64] = pxw + rd + bias_r;
            if (t == Tc - 1) {
                #pragma unroll
                for (int r = 0; r < 16; ++r)
                    Ffin[((size_t)bg * Hc + c0 + fci) * 16 + r] = F_lds[j64][r];
            } else {
                const size_t row = (size_t)bg * Tc + (t + 1);
                plam = lamg[row];
                pv   = vg[row * Hc + c0 + fci];
                pxw  = out0[row * Hc + c0 + fci];
                const float* qp  = qg + row * 16;
                const float* kpp = kg + row * 16;
                #pragma unroll
                for (int r4 = 0; r4 < 4; ++r4) {
                    pq[r4]  = *(const float4*)(qp + r4 * 4);
                    pk4[r4] = *(const float4*)(kpp + r4 * 4);
                }
            }
        }

        // ---- poll own 8-value window, stage into hs ----
        if (t > 0) {
            const float lo = off_r - 1.5f, hi = off_r + 1.5f;
            const float* p0 = h_rd + sb_ * 1024 + f;
            const float* p1 = p0 + 4;
            float4 r0, r1;
            int tries = 0;
            for (;;) {
                if (fastf) {
                    asm volatile(
                        "global_load_dwordx4 %0, %2, off sc0\n\t"
                        "global_load_dwordx4 %1, %3, off sc0\n\t"
                        "s_waitcnt vmcnt(0)"
                        : "=&v"(r0), "=&v"(r1)
                        : "v"(p0), "v"(p1) : "memory");
                } else {
                    asm volatile(
                        "global_load_dwordx4 %0, %2, off sc0 sc1\n\t"
                        "global_load_dwordx4 %1, %3, off sc0 sc1\n\t"
                        "s_waitcnt vmcnt(0)"
                        : "=&v"(r0), "=&v"(r1)
                        : "v"(p0), "v"(p1) : "memory");
                }
                bool ok = r0.x > lo && r0.x < hi && r0.y > lo && r0.y < hi
                       && r0.z > lo && r0.z < hi && r0.w > lo && r0.w < hi
                       && r1.x > lo && r1.x < hi && r1.y > lo && r1.y < hi
                       && r1.z > lo && r1.z < hi && r1.w > lo && r1.w < hi;
                if (ok) break;
                if (fastf && ++tries > 64) fastf = 0;  // sticky escalation
            }
            r0.x -= off_r; r0.y -= off_r; r0.z -= off_r; r0.w -= off_r;
            r1.x -= off_r; r1.y -= off_r; r1.z -= off_r; r1.w -= off_r;
            *(float4*)(stage_base)     = r0;
            *(float4*)(stage_base + 4) = r1;
        } else {
            float4 z = {0.f, 0.f, 0.f, 0.f};
            *(float4*)(stage_base)     = z;
            *(float4*)(stage_base + 4) = z;
        }
        __syncthreads();                       // B: hs ready

        // ---- matvec: 16 b128 LDS reads, 256 FMAs per thread ----
        float acc[8];
        #pragma unroll
        for (int z = 0; z < 8; ++z) acc[z] = 0.f;
        #pragma unroll
        for (int bb = 0; bb < 2; ++bb) {
            const float* hb = &hs[bb * 1152 + kp * 36];
            #pragma unroll
            for (int i = 0; i < 8; ++i) {
                float4 h4 = *(const float4*)(hb + i * 4);
                #pragma unroll
                for (int j = 0; j < 4; ++j)
                    acc[j * 2 + bb] += h4.x * wr[(i * 4 + 0) * 4 + j]
                                     + h4.y * wr[(i * 4 + 1) * 4 + j]
                                     + h4.z * wr[(i * 4 + 2) * 4 + j]
                                     + h4.w * wr[(i * 4 + 3) * 4 + j];
            }
        }

        // ---- butterfly over the wave's 8 k-parts (lane bits 3,4,5) ----
        #pragma unroll
        for (int z = 0; z < 8; ++z) {
            float s = acc[z];
            s += __shfl_xor(s, 8);
            s += __shfl_xor(s, 16);
            s += __shfl_xor(s, 32);
            acc[z] = s;
        }
        if (j64 < 8) {                          // one lane per cu
            float4 ra, rb;
            ra.x = acc[0]; ra.y = acc[1]; ra.z = acc[2]; ra.w = acc[3];
            rb.x = acc[4]; rb.y = acc[5]; rb.z = acc[6]; rb.w = acc[7];
            *(float4*)&red2[buf][wv * 64 + j64 * 8]     = ra;
            *(float4*)&red2[buf][wv * 64 + j64 * 8 + 4] = rb;
        }
        __syncthreads();                       // C: red2 + pre_lds ready

        // ---- finisher: combine 4 wave-partials, tanh, store ----
        if (isFin) {
            const int cu_f = fci >> 2, jf = fci & 3;
            const int z = jf * 2 + fb;
            float tot = pre_lds[buf][j64];
            #pragma unroll
            for (int ww = 0; ww < 4; ++ww)
                tot += red2[buf][ww * 64 + cu_f * 8 + z];
            float hv = tanhf(tot);
            float sv = hv + off_w;             // self-signaling store first
            float* hp = h_wr + fb * 1024 + c0 + fci;
            asm volatile(
                "global_store_dword %0, %1, off sc0 sc1"
                :: "v"(hp), "v"(sv) : "memory");
            size_t oidx = ((size_t)bg * Tc + t) * Hc + c0 + fci;
            out0[oidx] = hv;
            if (t == Tc - 1) hfin[(size_t)bg * Hc + c0 + fci] = hv;
        }
    }
}

// ---------------------------------------------------------------------------
extern "C" void kernel_launch(void* const* d_in, const int* in_sizes, int n_in,
                              void* d_out, int out_size, void* d_ws, size_t ws_size,
                              hipStream_t stream)
{
    const float* x    = (const float*)d_in[0];
    const float* Wx   = (const float*)d_in[1];
    const float* Wh   = (const float*)d_in[2];
    const float* Wq   = (const float*)d_in[3];
    const float* Wk   = (const float*)d_in[4];
    const float* Wv   = (const float*)d_in[5];
    const float* Wd   = (const float*)d_in[6];
    const float* bias = (const float*)d_in[7];
    const float* bd   = (const float*)d_in[8];

    float* out0 = (float*)d_out;                    // (B,T,H): xw, then h
    float* hfin = out0 + (size_t)Bc * Tc * Hc;      // (B,H)
    float* Ffin = hfin + (size_t)Bc * Hc;           // (B,H,R)

    float* wsf  = (float*)d_ws;
    float* v    = wsf;                               // B*T*H
    float* q    = v + (size_t)Bc * Tc * Hc;          // B*T*R
    float* k    = q + (size_t)Bc * Tc * Rc;          // B*T*R
    float* lam  = k + (size_t)Bc * Tc * Rc;          // B*T
    float* hbuf = lam + (size_t)Bc * Tc;             // 2 * B*H ping-pong
    int*   xcc  = (int*)(hbuf + 2 * (size_t)Bc * Hc);// 256 entries

    // 0x7F7F7F7F == 3.39e38f: invalid under both offsets -> poll-safe init.
    hipMemsetAsync(hbuf, 0x7F, 2 * (size_t)Bc * Hc * sizeof(float), stream);
    hipMemsetAsync(xcc, 0xFF, 256 * sizeof(int), stream);

    dim3 gg(256, 16);
    gemm_xw<<<gg, 256, 0, stream>>>(x, Wx, out0);   // xw -> out0
    gemm_xw<<<gg, 256, 0, stream>>>(x, Wv, v);      // v  -> ws
    qkl_kernel<<<4096, 256, 0, stream>>>(x, Wq, Wk, Wd, bd, q, k, lam);
    rec_fused<<<256, 256, 0, stream>>>(Wh, q, k, v, lam, bias,
                                       out0, hfin, Ffin, hbuf, xcc);
}